// Round 10
// baseline (5361.095 us; speedup 1.0000x reference)
//
#include <hip/hip_runtime.h>
#include <float.h>

#define N_PTS   50000
#define M_CENT  2048
#define K_LOC   32
#define C_CH    128

typedef unsigned long long u64;
typedef unsigned int u32;

// ------- FPS: single-block, chunk-pruned, wave-owned, 12^3 grid (R10) -----
// R7-R9 (all absmax 0.0) converged to ~5400 cyc/iter regardless of
// instruction count -> Phase B global traffic/latency bound:
// active-set ~ ball(r_i + cell_diag); 8^3 diag 0.216 dominated r_i.
// R10: (1) 12^3 cells (diag 0.144) + 64-pt chunks -> ~3x fewer active
// points; (2) dist packed into spp.w (16B read + cond. 4B write per point;
// orig-idx loaded lazily for the argmax lane only); (3) Phase B software
// pipeline (prefetch next chunk's points during current reduce).
//
// Exactness unchanged: skip chunk iff 0.999*LB(bbox,c) >= chunk_max
// (conservative: then min(dist_j, d2_ref) == dist_j bit-identically for all
// j in chunk; 1e-3 margin >> f32 rounding). Active chunks recompute d2 with
// the exact reference arithmetic (fsub/fmul/fadd, ((xx+yy)+zz)). Ties ->
// min ORIGINAL idx via key (dist_bits<<32 | ~idx); unique-argmax fast path
// + exact reduce fallback. Winner sequence bit-identical to reference.
#define G_DIM   12
#define N_CELL  (G_DIM*G_DIM*G_DIM)   // 1728
#define CHUNK_CAP 64
#define SLOT_W  160                   // per-wave slot region
#define NC_MAX  (SLOT_W*16)           // 2560 >= 1728 + 50000/64 = 2509 worst
#define FPS1_NT 1024
#define NWAVE   (FPS1_NT/64)          // 16

__device__ __forceinline__ int cell_of(float x, float y, float z) {
  int a = (int)(x * (float)G_DIM);
  int b = (int)(y * (float)G_DIM);
  int c = (int)(z * (float)G_DIM);
  a = a < 0 ? 0 : (a > G_DIM-1 ? G_DIM-1 : a);
  b = b < 0 ? 0 : (b > G_DIM-1 ? G_DIM-1 : b);
  c = c < 0 ? 0 : (c > G_DIM-1 ? G_DIM-1 : c);
  return (a * G_DIM + b) * G_DIM + c;
}

// ---- DPP wave-wide reductions (ctrl must be a literal constant) ----
template <int CTRL>
__device__ __forceinline__ u32 dppmov_u(u32 v) {
  return (u32)__builtin_amdgcn_update_dpp((int)v, (int)v, CTRL, 0xf, 0xf, false);
}
template <int CTRL>
__device__ __forceinline__ float dppmov_f(float v) {
  return __int_as_float(
      __builtin_amdgcn_update_dpp(__float_as_int(v), __float_as_int(v),
                                  CTRL, 0xf, 0xf, false));
}
__device__ __forceinline__ float wave_max_f32(float v) {
  v = fmaxf(v, dppmov_f<0x111>(v));
  v = fmaxf(v, dppmov_f<0x112>(v));
  v = fmaxf(v, dppmov_f<0x114>(v));
  v = fmaxf(v, dppmov_f<0x118>(v));
  v = fmaxf(v, dppmov_f<0x142>(v));
  v = fmaxf(v, dppmov_f<0x143>(v));
  return __int_as_float(__builtin_amdgcn_readlane(__float_as_int(v), 63));
}
__device__ __forceinline__ float wave_min_f32(float v) {
  v = fminf(v, dppmov_f<0x111>(v));
  v = fminf(v, dppmov_f<0x112>(v));
  v = fminf(v, dppmov_f<0x114>(v));
  v = fminf(v, dppmov_f<0x118>(v));
  v = fminf(v, dppmov_f<0x142>(v));
  v = fminf(v, dppmov_f<0x143>(v));
  return __int_as_float(__builtin_amdgcn_readlane(__float_as_int(v), 63));
}
__device__ __forceinline__ u32 wave_min_u32(u32 v) {
  u32 t;
  t = dppmov_u<0x111>(v); v = v < t ? v : t;
  t = dppmov_u<0x112>(v); v = v < t ? v : t;
  t = dppmov_u<0x114>(v); v = v < t ? v : t;
  t = dppmov_u<0x118>(v); v = v < t ? v : t;
  t = dppmov_u<0x142>(v); v = v < t ? v : t;
  t = dppmov_u<0x143>(v); v = v < t ? v : t;
  return (u32)__builtin_amdgcn_readlane((int)v, 63);
}
template <int CTRL>
__device__ __forceinline__ u64 dpp_u64(u64 v) {
  u32 hi = dppmov_u<CTRL>((u32)(v >> 32));
  u32 lo = dppmov_u<CTRL>((u32)v);
  return ((u64)hi << 32) | (u64)lo;
}
__device__ __forceinline__ u64 wave_max_u64(u64 v) {
  u64 t;
  t = dpp_u64<0x111>(v); if (t > v) v = t;
  t = dpp_u64<0x112>(v); if (t > v) v = t;
  t = dpp_u64<0x114>(v); if (t > v) v = t;
  t = dpp_u64<0x118>(v); if (t > v) v = t;
  t = dpp_u64<0x142>(v); if (t > v) v = t;
  t = dpp_u64<0x143>(v); if (t > v) v = t;
  u32 rh = (u32)__builtin_amdgcn_readlane((int)(v >> 32), 63);
  u32 rl = (u32)__builtin_amdgcn_readlane((int)(v & 0xFFFFFFFFull), 63);
  return ((u64)rh << 32) | (u64)rl;
}

// ---------------- prep kernels ----------------
__global__ void init_zero_kernel(int* __restrict__ p, int n) {
  int t = blockIdx.x * blockDim.x + threadIdx.x;
  if (t < n) p[t] = 0;
}

__global__ void hist_kernel(const float* __restrict__ pos,
                            int* __restrict__ cellcnt) {
  int n = blockIdx.x * blockDim.x + threadIdx.x;
  if (n >= N_PTS) return;
  atomicAdd(&cellcnt[cell_of(pos[3*n], pos[3*n+1], pos[3*n+2])], 1);
}

__global__ __launch_bounds__(1024) void scan_kernel(
    const int* __restrict__ cellcnt, int* __restrict__ cursor,
    int2* __restrict__ rng, int* __restrict__ ncp)
{
  __shared__ int s[2048];
  const int tid = threadIdx.x;
  int c0 = (tid < N_CELL) ? cellcnt[tid] : 0;
  int c1 = (tid + 1024 < N_CELL) ? cellcnt[tid + 1024] : 0;
  s[tid] = c0; s[tid + 1024] = c1;
  __syncthreads();
  for (int off = 1; off < 2048; off <<= 1) {      // inclusive scan (counts)
    int a0 = (tid >= off) ? s[tid - off] : 0;
    int a1 = (tid + 1024 >= off) ? s[tid + 1024 - off] : 0;
    __syncthreads();
    s[tid] += a0; s[tid + 1024] += a1;
    __syncthreads();
  }
  int pofs0 = s[tid] - c0, pofs1 = s[tid + 1024] - c1;
  int nch0 = (c0 + CHUNK_CAP - 1) / CHUNK_CAP;
  int nch1 = (c1 + CHUNK_CAP - 1) / CHUNK_CAP;
  __syncthreads();
  s[tid] = nch0; s[tid + 1024] = nch1;
  __syncthreads();
  for (int off = 1; off < 2048; off <<= 1) {      // inclusive scan (chunks)
    int a0 = (tid >= off) ? s[tid - off] : 0;
    int a1 = (tid + 1024 >= off) ? s[tid + 1024 - off] : 0;
    __syncthreads();
    s[tid] += a0; s[tid + 1024] += a1;
    __syncthreads();
  }
  int chb0 = s[tid] - nch0, chb1 = s[tid + 1024] - nch1;
  if (tid < N_CELL) {
    cursor[tid] = pofs0;
    for (int k = 0; k < nch0; k++) {
      int rem = c0 - k * CHUNK_CAP;
      rng[chb0 + k] = make_int2(pofs0 + k * CHUNK_CAP,
                                rem < CHUNK_CAP ? rem : CHUNK_CAP);
    }
  }
  if (tid + 1024 < N_CELL) {
    cursor[tid + 1024] = pofs1;
    for (int k = 0; k < nch1; k++) {
      int rem = c1 - k * CHUNK_CAP;
      rng[chb1 + k] = make_int2(pofs1 + k * CHUNK_CAP,
                                rem < CHUNK_CAP ? rem : CHUNK_CAP);
    }
  }
  if (tid == 1023) *ncp = s[2047];                // total chunk count
}

__global__ void scatter_kernel(const float* __restrict__ pos,
    int* __restrict__ cursor, float4* __restrict__ spp,
    int* __restrict__ sidx)
{
  int n = blockIdx.x * blockDim.x + threadIdx.x;
  if (n >= N_PTS) return;
  float x = pos[3*n], y = pos[3*n+1], z = pos[3*n+2];
  int p = atomicAdd(&cursor[cell_of(x, y, z)], 1);
  spp[p] = make_float4(x, y, z, FLT_MAX);   // .w = running dist (ref init)
  sidx[p] = n;
}

__global__ __launch_bounds__(64) void bbox_kernel(
    const float4* __restrict__ spp, const int2* __restrict__ rng,
    const int* __restrict__ ncp,
    float4* __restrict__ bb_lo, float4* __restrict__ bb_hi)
{
  const int b = blockIdx.x, lane = threadIdx.x;
  int NC = *ncp;
  if (b >= NC) return;
  int2 rc = rng[b];
  bool v = lane < rc.y;
  float4 P = v ? spp[rc.x + lane] : make_float4(0,0,0,0);
  float lx = wave_min_f32(v ? P.x :  FLT_MAX);
  float ly = wave_min_f32(v ? P.y :  FLT_MAX);
  float lz = wave_min_f32(v ? P.z :  FLT_MAX);
  float hx = wave_max_f32(v ? P.x : -FLT_MAX);
  float hy = wave_max_f32(v ? P.y : -FLT_MAX);
  float hz = wave_max_f32(v ? P.z : -FLT_MAX);
  if (lane == 0) {
    bb_lo[b] = make_float4(lx, ly, lz, 0.f);
    bb_hi[b] = make_float4(hx, hy, hz, 0.f);
  }
}

// ---------------- the FPS kernel ----------------
__global__ __launch_bounds__(FPS1_NT) void fps_kernel(
    const float* __restrict__ pos,
    float4* __restrict__ spp, const int* __restrict__ sidx,
    const int2* __restrict__ rng,
    const float4* __restrict__ bb_lo, const float4* __restrict__ bb_hi,
    const int* __restrict__ ncp, float* __restrict__ cent_out)
{
  // chunk c: owner wave = c%16, j = c/16 (<160), slot p = (c%16)*160 + j
  __shared__ u64    l_key[NC_MAX];    // (maxdist_bits<<32) | ~minidx
  __shared__ int2   l_rng[NC_MAX];
  __shared__ float  l_blx[NC_MAX], l_bly[NC_MAX], l_blz[NC_MAX];
  __shared__ float  l_bhx[NC_MAX], l_bhy[NC_MAX], l_bhz[NC_MAX];
  __shared__ float  l_wcx[NC_MAX], l_wcy[NC_MAX], l_wcz[NC_MAX];
  __shared__ u64    l_red[NWAVE];
  __shared__ float4 l_rco[NWAVE];
  __shared__ float4 l_winco;

  const int tid = threadIdx.x, lane = tid & 63, wv = tid >> 6;
  const int NC = *ncp;                // <= 2509 structurally
  const int base = wv * SLOT_W;

  for (int p = tid; p < NC_MAX; p += FPS1_NT) {   // safe defaults everywhere
    l_key[p] = 0ull;
    l_blx[p] = 0.f; l_bly[p] = 0.f; l_blz[p] = 0.f;
    l_bhx[p] = 0.f; l_bhy[p] = 0.f; l_bhz[p] = 0.f;
    l_wcx[p] = 0.f; l_wcy[p] = 0.f; l_wcz[p] = 0.f;
  }
  __syncthreads();
  for (int c = tid; c < NC; c += FPS1_NT) {
    int p = (c & 15) * SLOT_W + (c >> 4);
    l_key[p] = ((u64)0x7F7FFFFFu) << 32;   // FLT_MAX: force iter-0 update
    l_rng[p] = rng[c];
    float4 lo = bb_lo[c], hi = bb_hi[c];
    l_blx[p] = lo.x; l_bly[p] = lo.y; l_blz[p] = lo.z;
    l_bhx[p] = hi.x; l_bhy[p] = hi.y; l_bhz[p] = hi.z;
  }
  __syncthreads();

  // iteration 0 centroid = point 0 (deterministic start, matches reference)
  float cx = pos[0], cy = pos[1], cz = pos[2];

  for (int i = 0; i < M_CENT; i++) {
    if (tid == 0) {
      cent_out[3*i+0] = cx; cent_out[3*i+1] = cy; cent_out[3*i+2] = cz;
    }
    if (i == M_CENT - 1) break;      // last winner never consumed (uniform)

    // ---- Phase A (wave-private): prune own slots, 3 ballot masks ----
    u64 m0 = 0, m1 = 0, m2 = 0;
#pragma unroll
    for (int k = 0; k < 3; k++) {
      int j = lane + (k << 6);
      int c = (j << 4) + wv;         // j*16 + wv
      bool act = false;
      if (c < NC) {
        int p = base + j;
        float cmax = __uint_as_float((u32)(l_key[p] >> 32));
        float ax = fmaxf(fmaxf(__fsub_rn(l_blx[p], cx),
                               __fsub_rn(cx, l_bhx[p])), 0.f);
        float ay = fmaxf(fmaxf(__fsub_rn(l_bly[p], cy),
                               __fsub_rn(cy, l_bhy[p])), 0.f);
        float az = fmaxf(fmaxf(__fsub_rn(l_blz[p], cz),
                               __fsub_rn(cz, l_bhz[p])), 0.f);
        float LB = (ax*ax + ay*ay + az*az) * 0.999f;  // conservative margin
        act = LB < cmax;             // NOT provably-skippable -> update
      }
      u64 m = __ballot(act);
      if (k == 0) m0 = m; else if (k == 1) m1 = m; else m2 = m;
    }

    // ---- Phase B (wave-private, pipelined): update own active chunks ----
    auto pop = [&]() -> int {        // wave-uniform (masks from ballots)
      if (m0) { int b = __ffsll((long long)m0)-1; m0 &= m0-1; return b; }
      if (m1) { int b = __ffsll((long long)m1)-1; m1 &= m1-1; return b+64; }
      if (m2) { int b = __ffsll((long long)m2)-1; m2 &= m2-1; return b+128; }
      return -1;
    };
    int j_c = pop();
    int2 rc_c = make_int2(0, 0);
    float4 P_c = make_float4(0,0,0,0);
    if (j_c >= 0) {
      rc_c = l_rng[base + j_c];
      if (lane < rc_c.y) P_c = spp[rc_c.x + lane];
    }
    while (j_c >= 0) {
      int j_n = pop();               // prefetch next chunk during reduce
      int2 rc_n = make_int2(0, 0);
      float4 P_n = make_float4(0,0,0,0);
      if (j_n >= 0) {
        rc_n = l_rng[base + j_n];
        if (lane < rc_n.y) P_n = spp[rc_n.x + lane];
      }
      // process current chunk
      bool v = lane < rc_c.y;
      int g = rc_c.x + lane;
      float dm = -1.f;
      if (v) {
        // exact reference arithmetic: no FMA, ((dx^2+dy^2)+dz^2)
        float dx = __fsub_rn(P_c.x, cx);
        float dy = __fsub_rn(P_c.y, cy);
        float dz = __fsub_rn(P_c.z, cz);
        float d2 = __fadd_rn(__fadd_rn(__fmul_rn(dx,dx), __fmul_rn(dy,dy)),
                             __fmul_rn(dz,dz));
        float dn = fminf(P_c.w, d2);
        if (dn < P_c.w) ((float*)(spp + g))[3] = dn;   // write only if changed
        dm = dn;
      }
      float wmax = wave_max_f32(dm);       // >= 0 (chunk non-empty)
      u32 hb = __float_as_uint(wmax);
      u64 tb = __ballot(dm == wmax);
      int p_c = base + j_c;
      if (__popcll(tb) == 1) {             // unique argmax lane (common)
        if (dm == wmax) {
          u32 mi = (u32)sidx[g];           // lazy orig-idx load (1 lane)
          l_key[p_c] = ((u64)hb << 32) | (u64)(~mi);
          l_wcx[p_c] = P_c.x; l_wcy[p_c] = P_c.y; l_wcz[p_c] = P_c.z;
        }
      } else {                             // exact tie fallback (rare)
        u32 cand = (dm == wmax) ? (u32)sidx[g] : 0xFFFFFFFFu;
        u32 minidx = wave_min_u32(cand);
        if (dm == wmax && cand == minidx) {  // unique: orig indices unique
          l_key[p_c] = ((u64)hb << 32) | (u64)(~minidx);
          l_wcx[p_c] = P_c.x; l_wcy[p_c] = P_c.y; l_wcz[p_c] = P_c.z;
        }
      }
      j_c = j_n; rc_c = rc_n; P_c = P_n;
    }

    // ---- Phase C1 (wave-private): wave winner over own slots ----
    {
      u64 kbest = 0ull; int pbest = base;
#pragma unroll
      for (int k = 0; k < 3; k++) {
        int j = lane + (k << 6);
        int c = (j << 4) + wv;
        if (c < NC) {
          int p = base + j;
          u64 kk = l_key[p];
          if (kk > kbest) { kbest = kk; pbest = p; }
        }
      }
      float kf = __uint_as_float((u32)(kbest >> 32));
      float km = wave_max_f32(kf);
      u64 cm = __ballot(kf == km);
      if (__popcll(cm) == 1) {             // unique dist-max (common)
        if (kf == km) {
          l_red[wv] = kbest;
          l_rco[wv] = make_float4(l_wcx[pbest], l_wcy[pbest], l_wcz[pbest], 0.f);
        }
      } else {                             // exact tie fallback (rare)
        u64 km64 = wave_max_u64(kbest);
        u64 bm = __ballot(kbest == km64);
        if (lane == __ffsll((long long)bm) - 1) {
          l_red[wv] = kbest;
          l_rco[wv] = make_float4(l_wcx[pbest], l_wcy[pbest], l_wcz[pbest], 0.f);
        }
      }
    }
    __syncthreads();
    // ---- Phase C2: wave0 reduces the 16 wave winners ----
    if (wv == 0) {
      u64 k = (lane < NWAVE) ? l_red[lane] : 0ull;
      u64 gm = wave_max_u64(k);
      u64 bm = __ballot(k == gm);
      if (lane == __ffsll((long long)bm) - 1) l_winco = l_rco[lane];
    }
    __syncthreads();
    cx = l_winco.x; cy = l_winco.y; cz = l_winco.z;
  }
}

// ---------------- Ball query ----------------
#define BQ_NT  256
#define BQ_CAP 2048   // expected ~209 candidates/centroid; huge safety margin

__global__ __launch_bounds__(BQ_NT) void ballq_kernel(
    const float* __restrict__ pos,
    const float* __restrict__ cent,   // centroid coords (from d_out)
    int* __restrict__ nbr,            // [M_CENT*K_LOC]
    int* __restrict__ nsel)           // [M_CENT]
{
  __shared__ float s_d2[BQ_CAP];
  __shared__ int   s_idx[BQ_CAP];
  __shared__ int   s_count;
  __shared__ u64   s_red[BQ_NT/64];
  __shared__ u64   s_win;

  const int m = blockIdx.x, tid = threadIdx.x;
  if (tid == 0) s_count = 0;
  __syncthreads();
  const float cx = cent[3*m+0], cy = cent[3*m+1], cz = cent[3*m+2];

  for (int n = tid; n < N_PTS; n += BQ_NT) {
    float dx = __fsub_rn(cx, pos[3*n+0]);
    float dy = __fsub_rn(cy, pos[3*n+1]);
    float dz = __fsub_rn(cz, pos[3*n+2]);
    float d2 = __fadd_rn(__fadd_rn(__fmul_rn(dx,dx), __fmul_rn(dy,dy)),
                         __fmul_rn(dz,dz));
    if (d2 <= 0.01f) {   // same f32 value as (float)(0.1*0.1)
      int p = atomicAdd(&s_count, 1);
      if (p < BQ_CAP) { s_d2[p] = d2; s_idx[p] = n; }
    }
  }
  __syncthreads();
  int cnt = s_count; if (cnt > BQ_CAP) cnt = BQ_CAP;
  int ns = cnt < K_LOC ? cnt : K_LOC;

  // exact top_k semantics: k smallest d2, ties -> smaller index
  for (int sel = 0; sel < ns; sel++) {
    u64 best = ~0ull;
    for (int p = tid; p < cnt; p += BQ_NT) {
      u64 pk = ((u64)__float_as_uint(s_d2[p]) << 32) | (u64)(u32)s_idx[p];
      if (pk < best) best = pk;
    }
#pragma unroll
    for (int off = 32; off >= 1; off >>= 1) {
      u64 o = __shfl_down(best, off, 64);
      if (o < best) best = o;
    }
    if ((tid & 63) == 0) s_red[tid >> 6] = best;
    __syncthreads();
    if (tid < 64) {
      best = (tid < BQ_NT/64) ? s_red[tid] : ~0ull;
#pragma unroll
      for (int off = 2; off >= 1; off >>= 1) {
        u64 o = __shfl_down(best, off, 64);
        if (o < best) best = o;
      }
      if (tid == 0) s_win = best;
    }
    __syncthreads();
    int widx = (int)(u32)(s_win & 0xFFFFFFFFull);
    if (tid == 0) nbr[m*K_LOC + sel] = widx;
    for (int p = tid; p < cnt; p += BQ_NT) {
      if (s_idx[p] == widx) s_d2[p] = FLT_MAX;   // remove winner
    }
    __syncthreads();
  }
  if (tid == 0) nsel[m] = ns;
}

// ---------------- Gather + max-pool + channel mix ----------------
// Max over the valid selected set == reference (fallback idx is the nearest
// valid neighbor, already a member of the set).
__global__ __launch_bounds__(C_CH) void pool_mix_kernel(
    const float* __restrict__ fs,   // (N,128,1)
    const float* __restrict__ fv,   // (N,128,3)
    const float* __restrict__ Ws,
    const float* __restrict__ Wv,
    const float* __restrict__ bs,
    const float* __restrict__ bv,
    const int* __restrict__ nbr,
    const int* __restrict__ nsel,
    float* __restrict__ out_s,      // (M,128,1)
    float* __restrict__ out_v)      // (M,128,3)
{
  __shared__ float ps[C_CH];
  __shared__ float pv[C_CH*3];
  const int m = blockIdx.x, o = threadIdx.x;
  const int ns = nsel[m];
  float mS = -FLT_MAX, m0 = -FLT_MAX, m1 = -FLT_MAX, m2 = -FLT_MAX;
  for (int j = 0; j < ns; j++) {
    int n = nbr[m*K_LOC + j];
    mS = fmaxf(mS, fs[(size_t)n*C_CH + o]);
    const float* r = fv + (size_t)n*(C_CH*3) + 3*o;
    m0 = fmaxf(m0, r[0]); m1 = fmaxf(m1, r[1]); m2 = fmaxf(m2, r[2]);
  }
  ps[o] = mS; pv[3*o+0] = m0; pv[3*o+1] = m1; pv[3*o+2] = m2;
  __syncthreads();
  float aS = bs[o];
  float a0 = bv[o], a1 = bv[o], a2 = bv[o];
  for (int cc = 0; cc < C_CH; cc++) {
    float w1 = Ws[cc*C_CH + o];
    float w2 = Wv[cc*C_CH + o];
    aS = fmaf(ps[cc], w1, aS);
    a0 = fmaf(pv[3*cc+0], w2, a0);
    a1 = fmaf(pv[3*cc+1], w2, a1);
    a2 = fmaf(pv[3*cc+2], w2, a2);
  }
  out_s[(size_t)m*C_CH + o] = aS;
  float* ov = out_v + (size_t)m*(C_CH*3) + 3*o;
  ov[0] = a0; ov[1] = a1; ov[2] = a2;
}

extern "C" void kernel_launch(void* const* d_in, const int* in_sizes, int n_in,
                              void* d_out, int out_size, void* d_ws, size_t ws_size,
                              hipStream_t stream) {
  (void)in_sizes; (void)n_in; (void)out_size; (void)ws_size;
  const float* pos = (const float*)d_in[0];
  const float* fs  = (const float*)d_in[1];
  const float* fv  = (const float*)d_in[2];
  const float* Ws  = (const float*)d_in[3];
  const float* Wv  = (const float*)d_in[4];
  const float* bs  = (const float*)d_in[5];
  const float* bv  = (const float*)d_in[6];

  float* out      = (float*)d_out;
  float* cent_out = out;                               // 2048*3
  float* out_s    = out + 3*M_CENT;                    // 2048*128
  float* out_v    = out + 3*M_CENT + M_CENT*C_CH;      // 2048*128*3

  // workspace layout (all offsets 256B-aligned)
  char* ws = (char*)d_ws;
  size_t off = 0;
  float4* spp  = (float4*)(ws + off); off += (size_t)50176 * 16;   // 802816
  int*   sidx  = (int*)  (ws + off);  off += (size_t)50176 * 4;
  int*   cellcnt = (int*)(ws + off);  off += 2048 * 4;
  int*   cursor  = (int*)(ws + off);  off += 2048 * 4;
  int*   ncp     = (int*)(ws + off);  off += 256;
  int2*  rng     = (int2*)(ws + off); off += (size_t)NC_MAX * 8;
  float4* bb_lo  = (float4*)(ws + off); off += (size_t)NC_MAX * 16;
  float4* bb_hi  = (float4*)(ws + off); off += (size_t)NC_MAX * 16;
  int*   nbr     = (int*)(ws + off); off += (size_t)M_CENT * K_LOC * 4;
  int*   nsel    = (int*)(ws + off); off += (size_t)M_CENT * 4;

  // zero cellcnt + cursor + ncp (contiguous: 2048+2048+64 ints)
  init_zero_kernel<<<(4160 + 255)/256, 256, 0, stream>>>(cellcnt, 4160);
  hist_kernel<<<(N_PTS + 255)/256, 256, 0, stream>>>(pos, cellcnt);
  scan_kernel<<<1, 1024, 0, stream>>>(cellcnt, cursor, rng, ncp);
  scatter_kernel<<<(N_PTS + 255)/256, 256, 0, stream>>>(pos, cursor, spp, sidx);
  bbox_kernel<<<NC_MAX, 64, 0, stream>>>(spp, rng, ncp, bb_lo, bb_hi);
  fps_kernel<<<1, FPS1_NT, 0, stream>>>(pos, spp, sidx, rng,
                                        bb_lo, bb_hi, ncp, cent_out);
  ballq_kernel<<<M_CENT, BQ_NT, 0, stream>>>(pos, cent_out, nbr, nsel);
  pool_mix_kernel<<<M_CENT, C_CH, 0, stream>>>(fs, fv, Ws, Wv, bs, bv,
                                               nbr, nsel, out_s, out_v);
}